// Round 13
// baseline (509.050 us; speedup 1.0000x reference)
//
#include <hip/hip_runtime.h>

#define FBANK_MEAN 15.41663f
#define FBANK_STD  6.55582f

constexpr int Bb   = 32;
constexpr int T    = 3200;
constexpr int D    = 128;
constexpr int C    = 512;    // embed_dim
constexpr int QD   = 256;    // quant_dim
constexpr int QN   = 1024;   // quant_n
constexpr int Tp   = 200;
constexpr int Fp   = 8;
constexpr int NTOK = Tp * Fp;     // 1600 tokens per batch
constexpr int TOKS = Bb * NTOK;   // 51200
constexpr int TPB  = 16;          // tokens per block

typedef float v4fe __attribute__((ext_vector_type(4)));

#define V4(p) (*(const v4fe*)(p))

// ---------------------------------------------------------------------------
// prep_a: [0,32): cbt transpose-normalize, 32 codes/block (R12-verified).
//         [32,288): M'[k][q] = sum_c W[c][k]proj[c][q]
//                              - mean_c(W[c][k]) * colsum(proj)[q]
//           W column staged in LDS first -> no serial latency chain.
//         288: embed_len.
__global__ void prep_a(const float* __restrict__ w, const float* __restrict__ proj,
                       const float* __restrict__ cb, const int* __restrict__ ilens,
                       float* __restrict__ Mp, float* __restrict__ cbt,
                       int* __restrict__ out_len) {
    const int bid = blockIdx.x, tid = threadIdx.x;
    if (bid < 32) {
        __shared__ float tile[32 * 257];    // padded stride: conflict-free
        __shared__ float nrm[32];
        const int k0 = bid * 32;
        const int lane = tid & 63, wv = tid >> 6;
        #pragma unroll 4
        for (int r = 0; r < 32; ++r)
            tile[r * 257 + tid] = cb[(size_t)(k0 + r) * QD + tid];
        __syncthreads();
        for (int c = 0; c < 8; ++c) {       // wave wv -> codes wv*8..+7
            int r = wv * 8 + c;
            float s = 0.f;
            #pragma unroll
            for (int m = 0; m < 4; ++m) {
                float v = tile[r * 257 + lane + 64 * m];
                s += v * v;
            }
            #pragma unroll
            for (int off = 32; off >= 1; off >>= 1) s += __shfl_xor(s, off);
            if (lane == 0) nrm[r] = rsqrtf(s + 1e-12f);
        }
        __syncthreads();
        const int c = tid & 31;
        #pragma unroll 4
        for (int it = 0; it < 32; ++it) {   // 8 d-rows x 32 codes per iter
            int d = it * 8 + (tid >> 5);
            cbt[d * QN + k0 + c] = tile[c * 257 + d] * nrm[c];
        }
    } else if (bid < 288) {
        __shared__ float wcol[C];
        const int k = bid - 32;             // patch-element row of M'
        // parallel gather of W column k (kills the serial latency chain)
        wcol[tid]       = w[(size_t)tid * 256 + k];
        wcol[tid + 256] = w[(size_t)(tid + 256) * 256 + k];
        __syncthreads();
        const int q = tid;
        float dot = 0.f, wsum = 0.f, psum = 0.f;
        #pragma unroll 8
        for (int cc = 0; cc < C; ++cc) {    // same order as R12: bitwise-identical
            float wv_ = wcol[cc];           // LDS broadcast
            float pv  = proj[cc * QD + q];  // coalesced
            dot  += wv_ * pv;
            wsum += wv_;
            psum += pv;
        }
        Mp[k * 256 + q] = dot - (wsum * (1.0f / 512.0f)) * psum;
    } else {
        if (tid < Bb) {
            int cnt = ilens[tid] >> 4;
            if (cnt > Tp) cnt = Tp;
            if (cnt < 0) cnt = 0;
            out_len[tid] = Fp * cnt;
        }
    }
}

// ---------------------------------------------------------------------------
// prep_b: G = M'(256x256) x cbt(256x1024).  128 blocks x 2 k-rows
// (was 64 x 4 -- doubles CU utilization; same accumulation order per (k,code)).
__global__ void prep_b(const float* __restrict__ Mp, const float* __restrict__ cbt,
                       float* __restrict__ G) {
    __shared__ __align__(16) float mrow[2 * 256];
    const int tid = threadIdx.x, lane = tid & 63, cq = tid >> 6;
    const int k0 = blockIdx.x * 2;
    mrow[tid]       = Mp[k0 * 256 + tid];          // row k0
    mrow[tid + 256] = Mp[(k0 + 1) * 256 + tid];    // row k0+1
    __syncthreads();
    v4fe acc[2];
    const v4fe zero4 = {0.f, 0.f, 0.f, 0.f};
    acc[0] = zero4; acc[1] = zero4;
    const float* cbase = cbt + cq * 256 + 4 * lane;
    for (int d4 = 0; d4 < 64; ++d4) {
        const int db = d4 * 4;
        v4fe w0 = V4(cbase + (db + 0) * QN);
        v4fe w1 = V4(cbase + (db + 1) * QN);
        v4fe w2 = V4(cbase + (db + 2) * QN);
        v4fe w3 = V4(cbase + (db + 3) * QN);
        v4fe xv[2];
        #pragma unroll
        for (int r = 0; r < 2; ++r) xv[r] = V4(mrow + r * 256 + db);
        #pragma unroll
        for (int r = 0; r < 2; ++r) {
            acc[r] += xv[r].x * w0;
            acc[r] += xv[r].y * w1;
            acc[r] += xv[r].z * w2;
            acc[r] += xv[r].w * w3;
        }
    }
    #pragma unroll
    for (int r = 0; r < 2; ++r)
        *(v4fe*)(G + (size_t)(k0 + r) * QN + cq * 256 + 4 * lane) = acc[r];
}

// ---------------------------------------------------------------------------
// fused_g: patch staging -> sims = patch x G (K=256) -> argmax.
// BYTE-IDENTICAL to round 12 (measured at 94% of the fp32 issue floor).
__global__ __launch_bounds__(256, 4) void fused_g(
    const float* __restrict__ xs,    // B*T*D
    const float* __restrict__ G,     // 256 x 1024 (k-major)
    int* __restrict__ out_ind)       // TOKS
{
    __shared__ __align__(16) float patch[TPB * 256];   // 16 KB
    __shared__ float rvs[4][TPB];
    __shared__ int   rif[4][TPB];

    const int tid  = threadIdx.x;
    const int lane = tid & 63;
    const int wv   = tid >> 6;               // wave id 0..3
    const int g0   = blockIdx.x * TPB;
    const int b    = g0 / NTOK;
    const int n0   = g0 - b * NTOK;
    const int tp0  = n0 >> 3;

    const v4fe zero4 = {0.f, 0.f, 0.f, 0.f};

    // ---- 1. patch staging (verified swizzle) ------------------------------
    {
        const v4fe* src = (const v4fe*)(xs + ((size_t)b * T + (size_t)tp0 * 16) * D);
        const float inv = 1.0f / (2.0f * FBANK_STD);
        #pragma unroll
        for (int r = 0; r < 4; ++r) {
            int f4 = r * 256 + tid;
            v4fe v = (src[f4] - FBANK_MEAN) * inv;
            int i = f4 >> 5;
            int d = (f4 & 31) << 2;
            int t = ((i >> 4) << 3) + (d >> 4);
            int k = ((i & 15) << 4) + (d & 15);
            *(v4fe*)&patch[t * 256 + k] = v;
        }
    }
    __syncthreads();

    // ---- 2. sims = patch x G: Mr=16 tok x 4 codes; waves = code-quarters --
    {
        const int cq = wv;
        v4fe acc[16];
        #pragma unroll
        for (int j = 0; j < 16; ++j) acc[j] = zero4;
        const float* cbase = G + cq * 256 + 4 * lane;
        for (int d4 = 0; d4 < 64; ++d4) {
            const int db = d4 * 4;
            v4fe w0 = V4(cbase + (db + 0) * QN);
            v4fe w1 = V4(cbase + (db + 1) * QN);
            v4fe w2 = V4(cbase + (db + 2) * QN);
            v4fe w3 = V4(cbase + (db + 3) * QN);
            #pragma unroll
            for (int hh = 0; hh < 2; ++hh) {
                v4fe xv[8];
                #pragma unroll
                for (int j = 0; j < 8; ++j)    // wave-uniform broadcasts
                    xv[j] = V4(patch + (hh * 8 + j) * 256 + db);
                #pragma unroll
                for (int j = 0; j < 8; ++j) {
                    acc[hh * 8 + j] += xv[j].x * w0;
                    acc[hh * 8 + j] += xv[j].y * w1;
                    acc[hh * 8 + j] += xv[j].z * w2;
                    acc[hh * 8 + j] += xv[j].w * w3;
                }
            }
        }
        // argmax: per-thread over 4 codes (ascending), 64-lane butterfly
        const int base = cq * 256 + 4 * lane;
        #pragma unroll
        for (int j = 0; j < 16; ++j) {
            float bv = acc[j].x; int bi = base;
            if (acc[j].y > bv) { bv = acc[j].y; bi = base + 1; }
            if (acc[j].z > bv) { bv = acc[j].z; bi = base + 2; }
            if (acc[j].w > bv) { bv = acc[j].w; bi = base + 3; }
            #pragma unroll
            for (int off = 32; off >= 1; off >>= 1) {
                float ov = __shfl_xor(bv, off);
                int   oi = __shfl_xor(bi, off);
                if (ov > bv || (ov == bv && oi < bi)) { bv = ov; bi = oi; }
            }
            if (lane == 0) { rvs[cq][j] = bv; rif[cq][j] = bi; }
        }
    }
    __syncthreads();
    if (tid < TPB) {
        float bv = rvs[0][tid];
        int   bi = rif[0][tid];
        #pragma unroll
        for (int w = 1; w < 4; ++w) {        // quarters ascending: strict >
            float ov = rvs[w][tid];
            if (ov > bv) { bv = ov; bi = rif[w][tid]; }
        }
        out_ind[g0 + tid] = bi;
    }
}

// ---------------------------------------------------------------------------
extern "C" void kernel_launch(void* const* d_in, const int* in_sizes, int n_in,
                              void* d_out, int out_size, void* d_ws, size_t ws_size,
                              hipStream_t stream) {
    const float* xs       = (const float*)d_in[0];   // (32,3200,128) f32
    const int*   ilens    = (const int*)  d_in[1];   // (32,) i32
    const float* conv_w   = (const float*)d_in[2];   // (512,1,16,16) f32
    const float* proj     = (const float*)d_in[3];   // (512,256) f32
    const float* codebook = (const float*)d_in[4];   // (1024,256) f32
    int* out = (int*)d_out;                          // 51200 ind + 32 len

    // Workspace 2.25 MB -- confirmed available (R12 rocprof shows fused_g ran,
    // i.e. the ws_size guard passed on this harness).
    float* cbt = (float*)d_ws;            // 256x1024 = 1 MB
    float* Mp  = cbt + QD * QN;           // 256x256  = 256 KB
    float* G   = Mp + 256 * 256;          // 256x1024 = 1 MB

    prep_a<<<289, 256, 0, stream>>>(conv_w, proj, codebook, ilens,
                                    Mp, cbt, out + TOKS);
    prep_b<<<128, 256, 0, stream>>>(Mp, cbt, G);
    fused_g<<<TOKS / TPB, 256, 0, stream>>>(xs, G, out);
}

// Round 14
// 463.718 us; speedup vs baseline: 1.0978x; 1.0978x over previous
//
#include <hip/hip_runtime.h>

#define FBANK_MEAN 15.41663f
#define FBANK_STD  6.55582f

constexpr int Bb   = 32;
constexpr int T    = 3200;
constexpr int D    = 128;
constexpr int C    = 512;    // embed_dim
constexpr int QD   = 256;    // quant_dim
constexpr int QN   = 1024;   // quant_n
constexpr int Tp   = 200;
constexpr int Fp   = 8;
constexpr int NTOK = Tp * Fp;     // 1600 tokens per batch
constexpr int TOKS = Bb * NTOK;   // 51200
constexpr int TPB  = 16;          // tokens per block

typedef float v4fe __attribute__((ext_vector_type(4)));

#define V4(p) (*(const v4fe*)(p))

// ---------------------------------------------------------------------------
// prep_a: [0,32): cbt transpose-normalize, 32 codes/block (R12-verified).
//         [32,288): M'[k][q] = sum_c W[c][k]proj[c][q]
//                              - mean_c(W[c][k]) * colsum(proj)[q]
//           R12 form: wave-uniform w read (s_load pipelined) + coalesced proj.
//           (R13's LDS-gather variant measured SLOWER -- reverted.)
//         288: embed_len.
__global__ void prep_a(const float* __restrict__ w, const float* __restrict__ proj,
                       const float* __restrict__ cb, const int* __restrict__ ilens,
                       float* __restrict__ Mp, float* __restrict__ cbt,
                       int* __restrict__ out_len) {
    const int bid = blockIdx.x, tid = threadIdx.x;
    if (bid < 32) {
        __shared__ float tile[32 * 257];    // padded stride: conflict-free
        __shared__ float nrm[32];
        const int k0 = bid * 32;
        const int lane = tid & 63, wv = tid >> 6;
        #pragma unroll 4
        for (int r = 0; r < 32; ++r)
            tile[r * 257 + tid] = cb[(size_t)(k0 + r) * QD + tid];
        __syncthreads();
        for (int c = 0; c < 8; ++c) {       // wave wv -> codes wv*8..+7
            int r = wv * 8 + c;
            float s = 0.f;
            #pragma unroll
            for (int m = 0; m < 4; ++m) {
                float v = tile[r * 257 + lane + 64 * m];
                s += v * v;
            }
            #pragma unroll
            for (int off = 32; off >= 1; off >>= 1) s += __shfl_xor(s, off);
            if (lane == 0) nrm[r] = rsqrtf(s + 1e-12f);
        }
        __syncthreads();
        const int c = tid & 31;
        #pragma unroll 4
        for (int it = 0; it < 32; ++it) {   // 8 d-rows x 32 codes per iter
            int d = it * 8 + (tid >> 5);
            cbt[d * QN + k0 + c] = tile[c * 257 + d] * nrm[c];
        }
    } else if (bid < 288) {
        int k = bid - 32;                   // patch-element row of M'
        int q = tid;
        float dot = 0.f, wsum = 0.f, psum = 0.f;
        #pragma unroll 4
        for (int cc = 0; cc < C; ++cc) {
            float wv_ = w[cc * 256 + k];    // wave-uniform (s_load, pipelined)
            float pv  = proj[cc * QD + q];  // coalesced
            dot  += wv_ * pv;
            wsum += wv_;
            psum += pv;
        }
        Mp[k * 256 + q] = dot - (wsum * (1.0f / 512.0f)) * psum;
    } else {
        if (tid < Bb) {
            int cnt = ilens[tid] >> 4;
            if (cnt > Tp) cnt = Tp;
            if (cnt < 0) cnt = 0;
            out_len[tid] = Fp * cnt;
        }
    }
}

// ---------------------------------------------------------------------------
// prep_b: G = M'(256x256) x cbt(256x1024).
// Tiled: 256 blocks = 16 k-tiles (16 rows, LDS-staged) x 16 code-tiles (64).
// Per-block reads: 16 KB M' + 64 KB cbt (was 1 MB cbt/block at 64-128 blocks
// in R12/R13 -- footprint was the bottleneck, not block count).
__global__ void prep_b(const float* __restrict__ Mp, const float* __restrict__ cbt,
                       float* __restrict__ G) {
    __shared__ __align__(16) float mt[16 * 256];   // 16 KB M' tile
    const int tid = threadIdx.x;
    const int kt = blockIdx.x >> 4;      // k-tile 0..15
    const int ct = blockIdx.x & 15;      // code-tile 0..15
    const int k0 = kt * 16;
    const int n  = ct * 64 + (tid & 63); // this thread's code
    const int wv = tid >> 6;             // wave -> 4 k-rows
    #pragma unroll
    for (int r = 0; r < 16; ++r)
        mt[r * 256 + tid] = Mp[(size_t)(k0 + r) * 256 + tid];
    __syncthreads();
    float acc[4] = {0.f, 0.f, 0.f, 0.f};
    for (int d4 = 0; d4 < 64; ++d4) {
        const int db = d4 * 4;
        float c0 = cbt[(size_t)(db + 0) * QN + n];   // coalesced across lane
        float c1 = cbt[(size_t)(db + 1) * QN + n];
        float c2 = cbt[(size_t)(db + 2) * QN + n];
        float c3 = cbt[(size_t)(db + 3) * QN + n];
        #pragma unroll
        for (int j = 0; j < 4; ++j) {
            v4fe m = V4(&mt[(wv * 4 + j) * 256 + db]);  // LDS broadcast b128
            acc[j] += m.x * c0;
            acc[j] += m.y * c1;
            acc[j] += m.z * c2;
            acc[j] += m.w * c3;
        }
    }
    #pragma unroll
    for (int j = 0; j < 4; ++j)
        G[(size_t)(k0 + wv * 4 + j) * QN + n] = acc[j];
}

// ---------------------------------------------------------------------------
// fused_g: patch staging -> sims = patch x G (K=256) -> argmax.
// BYTE-IDENTICAL to rounds 12/13 (measured 343 us, 94% of fp32 issue floor).
__global__ __launch_bounds__(256, 4) void fused_g(
    const float* __restrict__ xs,    // B*T*D
    const float* __restrict__ G,     // 256 x 1024 (k-major)
    int* __restrict__ out_ind)       // TOKS
{
    __shared__ __align__(16) float patch[TPB * 256];   // 16 KB
    __shared__ float rvs[4][TPB];
    __shared__ int   rif[4][TPB];

    const int tid  = threadIdx.x;
    const int lane = tid & 63;
    const int wv   = tid >> 6;               // wave id 0..3
    const int g0   = blockIdx.x * TPB;
    const int b    = g0 / NTOK;
    const int n0   = g0 - b * NTOK;
    const int tp0  = n0 >> 3;

    const v4fe zero4 = {0.f, 0.f, 0.f, 0.f};

    // ---- 1. patch staging (verified swizzle) ------------------------------
    {
        const v4fe* src = (const v4fe*)(xs + ((size_t)b * T + (size_t)tp0 * 16) * D);
        const float inv = 1.0f / (2.0f * FBANK_STD);
        #pragma unroll
        for (int r = 0; r < 4; ++r) {
            int f4 = r * 256 + tid;
            v4fe v = (src[f4] - FBANK_MEAN) * inv;
            int i = f4 >> 5;
            int d = (f4 & 31) << 2;
            int t = ((i >> 4) << 3) + (d >> 4);
            int k = ((i & 15) << 4) + (d & 15);
            *(v4fe*)&patch[t * 256 + k] = v;
        }
    }
    __syncthreads();

    // ---- 2. sims = patch x G: Mr=16 tok x 4 codes; waves = code-quarters --
    {
        const int cq = wv;
        v4fe acc[16];
        #pragma unroll
        for (int j = 0; j < 16; ++j) acc[j] = zero4;
        const float* cbase = G + cq * 256 + 4 * lane;
        for (int d4 = 0; d4 < 64; ++d4) {
            const int db = d4 * 4;
            v4fe w0 = V4(cbase + (db + 0) * QN);
            v4fe w1 = V4(cbase + (db + 1) * QN);
            v4fe w2 = V4(cbase + (db + 2) * QN);
            v4fe w3 = V4(cbase + (db + 3) * QN);
            #pragma unroll
            for (int hh = 0; hh < 2; ++hh) {
                v4fe xv[8];
                #pragma unroll
                for (int j = 0; j < 8; ++j)    // wave-uniform broadcasts
                    xv[j] = V4(patch + (hh * 8 + j) * 256 + db);
                #pragma unroll
                for (int j = 0; j < 8; ++j) {
                    acc[hh * 8 + j] += xv[j].x * w0;
                    acc[hh * 8 + j] += xv[j].y * w1;
                    acc[hh * 8 + j] += xv[j].z * w2;
                    acc[hh * 8 + j] += xv[j].w * w3;
                }
            }
        }
        // argmax: per-thread over 4 codes (ascending), 64-lane butterfly
        const int base = cq * 256 + 4 * lane;
        #pragma unroll
        for (int j = 0; j < 16; ++j) {
            float bv = acc[j].x; int bi = base;
            if (acc[j].y > bv) { bv = acc[j].y; bi = base + 1; }
            if (acc[j].z > bv) { bv = acc[j].z; bi = base + 2; }
            if (acc[j].w > bv) { bv = acc[j].w; bi = base + 3; }
            #pragma unroll
            for (int off = 32; off >= 1; off >>= 1) {
                float ov = __shfl_xor(bv, off);
                int   oi = __shfl_xor(bi, off);
                if (ov > bv || (ov == bv && oi < bi)) { bv = ov; bi = oi; }
            }
            if (lane == 0) { rvs[cq][j] = bv; rif[cq][j] = bi; }
        }
    }
    __syncthreads();
    if (tid < TPB) {
        float bv = rvs[0][tid];
        int   bi = rif[0][tid];
        #pragma unroll
        for (int w = 1; w < 4; ++w) {        // quarters ascending: strict >
            float ov = rvs[w][tid];
            if (ov > bv) { bv = ov; bi = rif[w][tid]; }
        }
        out_ind[g0 + tid] = bi;
    }
}

// ---------------------------------------------------------------------------
extern "C" void kernel_launch(void* const* d_in, const int* in_sizes, int n_in,
                              void* d_out, int out_size, void* d_ws, size_t ws_size,
                              hipStream_t stream) {
    const float* xs       = (const float*)d_in[0];   // (32,3200,128) f32
    const int*   ilens    = (const int*)  d_in[1];   // (32,) i32
    const float* conv_w   = (const float*)d_in[2];   // (512,1,16,16) f32
    const float* proj     = (const float*)d_in[3];   // (512,256) f32
    const float* codebook = (const float*)d_in[4];   // (1024,256) f32
    int* out = (int*)d_out;                          // 51200 ind + 32 len

    // Workspace 2.25 MB -- confirmed available (R12/R13 ran fused_g).
    float* cbt = (float*)d_ws;            // 256x1024 = 1 MB
    float* Mp  = cbt + QD * QN;           // 256x256  = 256 KB
    float* G   = Mp + 256 * 256;          // 256x1024 = 1 MB

    prep_a<<<289, 256, 0, stream>>>(conv_w, proj, codebook, ilens,
                                    Mp, cbt, out + TOKS);
    prep_b<<<256, 256, 0, stream>>>(Mp, cbt, G);
    fused_g<<<TOKS / TPB, 256, 0, stream>>>(xs, G, out);
}